// Round 8
// baseline (208.058 us; speedup 1.0000x reference)
//
#include <hip/hip_runtime.h>
#include <hip/hip_fp16.h>
#include <math.h>

#define NB 32
#define NC 3
#define HH 512
#define WW 512
#define W2 272   // padded half-spectrum width: cols 0..256 valid, 257..271 pad
#define NT 9     // col-kernel tiles per image: 8 x 32-wide + 1 x 16-wide (Nyquist)

typedef __half2 h2;
typedef unsigned long long ull;

// ---------- helpers ----------

// XOR swizzle for per-line LDS FFT: 2-way (free) bank conflicts on all 3 stages
__device__ __forceinline__ int swz(int i){ int h=(i>>6)&7; return i ^ (h<<3) ^ h; }
// base-8 digit reversal of 9-bit index
__device__ __forceinline__ int rev9(int k){ return ((k&7)<<6) | (k&56) | (k>>6); }

__device__ __forceinline__ float sin2pi(float x){
#if __has_builtin(__builtin_amdgcn_sinf)
  return __builtin_amdgcn_sinf(x);
#else
  return __sinf(6.28318530717958647692f*x);
#endif
}
__device__ __forceinline__ float cos2pi(float x){
#if __has_builtin(__builtin_amdgcn_cosf)
  return __builtin_amdgcn_cosf(x);
#else
  return __cosf(6.28318530717958647692f*x);
#endif
}

// unnormalized 8-point DFT. S=-1: forward; S=+1: conjugate (8*inverse)
template<int S>
__device__ __forceinline__ void dft8(float* xr, float* xi){
  const float r2 = 0.70710678118654752f;
  float tr[4], ti[4], mr[4], mi[4];
#pragma unroll
  for(int n=0;n<4;n++){
    tr[n]=xr[n]+xr[n+4]; ti[n]=xi[n]+xi[n+4];
    mr[n]=xr[n]-xr[n+4]; mi[n]=xi[n]-xi[n+4];
  }
  float or_[4], oi_[4];
  or_[0]=mr[0];               oi_[0]=mi[0];
  or_[1]=r2*(mr[1]-S*mi[1]);  oi_[1]=r2*(mi[1]+S*mr[1]);
  or_[2]=-S*mi[2];            oi_[2]= S*mr[2];
  or_[3]=-r2*(mr[3]+S*mi[3]); oi_[3]= r2*(S*mr[3]-mi[3]);
  float s0r=tr[0]+tr[2], s0i=ti[0]+ti[2];
  float s1r=tr[1]+tr[3], s1i=ti[1]+ti[3];
  float d0r=tr[0]-tr[2], d0i=ti[0]-ti[2];
  float d1r=tr[1]-tr[3], d1i=ti[1]-ti[3];
  xr[0]=s0r+s1r;   xi[0]=s0i+s1i;
  xr[4]=s0r-s1r;   xi[4]=s0i-s1i;
  xr[2]=d0r-S*d1i; xi[2]=d0i+S*d1r;
  xr[6]=d0r+S*d1i; xi[6]=d0i-S*d1r;
  float p0r=or_[0]+or_[2], p0i=oi_[0]+oi_[2];
  float p1r=or_[1]+or_[3], p1i=oi_[1]+oi_[3];
  float e0r=or_[0]-or_[2], e0i=oi_[0]-oi_[2];
  float e1r=or_[1]-or_[3], e1i=oi_[1]-oi_[3];
  xr[1]=p0r+p1r;   xi[1]=p0i+p1i;
  xr[5]=p0r-p1r;   xi[5]=p0i-p1i;
  xr[3]=e0r-S*e1i; xi[3]=e0i+S*e1r;
  xr[7]=e0r+S*e1i; xi[7]=e0i-S*e1r;
}

template<int S>
__device__ __forceinline__ void twid(float* xr, float* xi, int n, float invM){
  float f = (float)n * invM;
  float c1 = cos2pi(f), s1 = (float)S * sin2pi(f);
  float cr=c1, ci=s1;
#pragma unroll
  for(int q=1;q<8;q++){
    float a=xr[q], b=xi[q];
    xr[q]=a*cr-b*ci; xi[q]=a*ci+b*cr;
    float nr=cr*c1-ci*s1, ni=cr*s1+ci*c1;
    cr=nr; ci=ni;
  }
}

// ---------- K1: paired-row real FFT -> half spectrum (half2, natural w 0..256) ----------
// 128 threads = 2 independent waves, per-wave LDS regions
__global__ __launch_bounds__(128) void k_row_rfft(const float* __restrict__ x, h2* __restrict__ Fh,
                                                  ull fh_cs){
  __shared__ float lre[2][512];
  __shared__ float lim[2][512];
  const int wv = threadIdx.x>>6, t = threadIdx.x&63;
  const int pr = blockIdx.x*2 + wv;             // pair index: b*256 + r2
  const int b = pr>>8, r2 = pr&255;
  const int cc = blockIdx.y;
  const float* sa = x + (size_t)b*(NC*HH*WW) + (size_t)cc*HH*WW + (size_t)(2*r2)*WW;
  const float* sb = sa + WW;
  float xr[8], xi[8];
#pragma unroll
  for(int i=0;i<8;i++){ xr[i]=sa[t+64*i]; xi[i]=sb[t+64*i]; }
  dft8<-1>(xr,xi);
  twid<-1>(xr,xi,t,1.0f/512.0f);
#pragma unroll
  for(int q=0;q<8;q++){ int p=swz(t+64*q); lre[wv][p]=xr[q]; lim[wv][p]=xi[q]; }
  __syncthreads();
  const int beta=t>>3, n1=t&7, base1=64*beta+n1;
#pragma unroll
  for(int i=0;i<8;i++){ int p=swz(base1+8*i); xr[i]=lre[wv][p]; xi[i]=lim[wv][p]; }
  dft8<-1>(xr,xi);
  twid<-1>(xr,xi,n1,1.0f/64.0f);
#pragma unroll
  for(int q=0;q<8;q++){ int p=swz(base1+8*q); lre[wv][p]=xr[q]; lim[wv][p]=xi[q]; }
  __syncthreads();
#pragma unroll
  for(int i=0;i<8;i++){ int p=swz(8*t+i); xr[i]=lre[wv][p]; xi[i]=lim[wv][p]; }
  dft8<-1>(xr,xi);
  __syncthreads();
  // scatter to natural order: slot 8t+i holds Z[rev9(8t+i)]
#pragma unroll
  for(int i=0;i<8;i++){ int nat = 64*i + 8*(t&7) + (t>>3); lre[wv][nat]=xr[i]; lim[wv][nat]=xi[i]; }
  __syncthreads();
  // Hermitian unpack: Ra[w]=(Z[w]+conj(Z[-w]))/2, Rb[w]=-i(Z[w]-conj(Z[-w]))/2
  h2* Fa = Fh + (size_t)cc*fh_cs + (size_t)(b*HH + 2*r2)*W2;
  h2* Fb = Fa + W2;
#pragma unroll
  for(int j=0;j<5;j++){
    int w = t + 64*j;
    if(w<=256){
      int m = (512-w)&511;
      float pr_=lre[wv][w], pi_=lim[wv][w], qr=lre[wv][m], qi=lim[wv][m];
      Fa[w]=__float22half2_rn(make_float2(0.5f*(pr_+qr), 0.5f*(pi_-qi)));
      Fb[w]=__float22half2_rn(make_float2(0.5f*(pi_+qi), 0.5f*(qr-pr_)));
    }
  }
}

// ---------- K2: column FFT (3-phase, 1024 thr, 32-col tiles, h2 LDS) ----------
__global__ __launch_bounds__(1024, 8) void k_col_fft(h2* __restrict__ Fh, ull fh_cs){
  __shared__ h2 sld[512*33];                    // 67.6 KB -> 2 blocks/CU, 32 waves/CU
  const int b    = blockIdx.x/NT;
  const int tile = blockIdx.x - b*NT;
  const int w0   = tile*32;
  const int cc   = blockIdx.y;
  h2* base = Fh + (size_t)cc*fh_cs + (size_t)b*HH*W2 + w0;
  const int c = threadIdx.x&31, w = threadIdx.x>>5;   // w in 0..31
  const int cl = (w0+c<=271) ? c : (271-w0);          // clamp pad lanes in-bounds
  const bool vst = (w0+c<=256);
#pragma unroll
  for(int jj=0;jj<2;jj++){                      // phase A: stage 0 from global
    int n = jj*32 + w;
    float xr[8], xi[8];
#pragma unroll
    for(int i=0;i<8;i++){ float2 v = __half22float2(base[(size_t)(n+64*i)*W2 + cl]); xr[i]=v.x; xi[i]=v.y; }
    dft8<-1>(xr,xi);
    twid<-1>(xr,xi,n,1.0f/512.0f);
#pragma unroll
    for(int q=0;q<8;q++){ int e=n+64*q; sld[e*33+c]=__float22half2_rn(make_float2(xr[q],xi[q])); }
  }
  __syncthreads();
#pragma unroll
  for(int jj=0;jj<2;jj++){                      // phase B: stage 1 in LDS
    int m = jj*32 + w;
    int bb = m>>3, nn = m&7, bs = 64*bb+nn;
    float xr[8], xi[8];
#pragma unroll
    for(int i=0;i<8;i++){ int e=bs+8*i; float2 v=__half22float2(sld[e*33+c]); xr[i]=v.x; xi[i]=v.y; }
    dft8<-1>(xr,xi);
    twid<-1>(xr,xi,nn,1.0f/64.0f);
#pragma unroll
    for(int q=0;q<8;q++){ int e=bs+8*q; sld[e*33+c]=__float22half2_rn(make_float2(xr[q],xi[q])); }
  }
  __syncthreads();
#pragma unroll
  for(int jj=0;jj<2;jj++){                      // phase C: stage 2 -> global
    int m = jj*32+w;
    float xr[8], xi[8];
#pragma unroll
    for(int i=0;i<8;i++){ int e=8*m+i; float2 v=__half22float2(sld[e*33+c]); xr[i]=v.x; xi[i]=v.y; }
    dft8<-1>(xr,xi);
    if(vst){
#pragma unroll
      for(int q=0;q<8;q++){
        int p=8*m+q;
        base[(size_t)p*W2+c]=__float22half2_rn(make_float2(xr[q],xi[q]));
      }
    }
  }
}

// ---------- K3: sum(running_amp) ----------
__global__ __launch_bounds__(256) void k_rsum(const float* __restrict__ ra, float* __restrict__ out, int n){
  float s=0.f;
  for(int i=blockIdx.x*256+threadIdx.x; i<n; i+=gridDim.x*256) s+=ra[i];
#pragma unroll
  for(int off=32;off>=1;off>>=1) s += __shfl_down(s, off, 64);
  if((threadIdx.x&63)==0) atomicAdd(out, s);
}

// ---------- K4: batch-mean |F| + symmetrized EMA amplitude A (float2-vectorized) ----------
__global__ __launch_bounds__(256) void k_amp(const h2* __restrict__ Fh, ull fh_cs,
                                             const float* __restrict__ ra, const float* __restrict__ rsum,
                                             float* __restrict__ A, ull a_cs){
  int f2 = blockIdx.x*256 + threadIdx.x;        // 0 .. 512*136-1 (pairs of cols)
  int p = f2/136, w2 = f2 - p*136;              // p = digit-rev h slot
  int w = 2*w2;                                 // natural col (even)
  const int cc = blockIdx.y;
  const float2* Fc = (const float2*)(Fh + (size_t)cc*fh_cs);
  float s0=0.f, s1=0.f;
#pragma unroll 8
  for(int b=0;b<NB;b++){
    float2 two = Fc[(size_t)b*(HH*W2/2) + f2];
    h2 va = ((const h2*)&two)[0], vb = ((const h2*)&two)[1];
    float2 a = __half22float2(va), bq = __half22float2(vb);
    s0 += sqrtf(a.x*a.x + a.y*a.y);
    s1 += sqrtf(bq.x*bq.x + bq.y*bq.y);
  }
  float mean0 = s0*(1.0f/32.0f), mean1 = s1*(1.0f/32.0f);
  const float* rac = ra + (size_t)cc*HH*WW;
  int h = rev9(p);
  int hs =(h+256)&511, hs2=(256-h)&511;
  int ws0 =(w+256)&511, ws20=(256-w)&511;
  int ws1 =(w+257)&511, ws21=(255-w)&511;
  float a0, a1;
  if(rsum[0]==0.0f){ a0=mean0; a1=mean1; }
  else{
    a0 = 0.45f*(rac[hs*WW+ws0] + rac[hs2*WW+ws20]) + 0.1f*mean0;
    a1 = 0.45f*(rac[hs*WW+ws1] + rac[hs2*WW+ws21]) + 0.1f*mean1;
  }
  *(float2*)(A + (size_t)cc*a_cs + (size_t)p*W2 + w) = make_float2(a0, a1);
}

// ---------- K5: magnitude substitution + column IFFT (3-phase, 1024 thr, 32-col tiles) ----------
__global__ __launch_bounds__(1024, 8) void k_col_ifft(h2* __restrict__ Fh, ull fh_cs,
                                                      const float* __restrict__ A, ull a_cs){
  __shared__ h2 sld[512*33];
  const int b    = blockIdx.x/NT;
  const int tile = blockIdx.x - b*NT;
  const int w0   = tile*32;
  const int cc   = blockIdx.y;
  h2* base = Fh + (size_t)cc*fh_cs + (size_t)b*HH*W2 + w0;
  const float* Aa = A + (size_t)cc*a_cs + w0;
  const int c = threadIdx.x&31, w = threadIdx.x>>5;
  const int cl = (w0+c<=271) ? c : (271-w0);
  const bool vst = (w0+c<=256);
  const float invN2 = 1.0f/262144.0f;
#pragma unroll
  for(int jj=0;jj<2;jj++){                      // phase A: scale + inverse stage 2, from global
    int m = jj*32+w;
    float xr[8], xi[8];
#pragma unroll
    for(int q=0;q<8;q++){
      int p=8*m+q;
      float2 v = __half22float2(base[(size_t)p*W2+cl]);
      float amp = Aa[(size_t)p*W2+cl];
      float m2 = v.x*v.x + v.y*v.y;
      float sc = amp*invN2*__frsqrt_rn(m2);
      if(m2 > 0.f){ xr[q]=v.x*sc; xi[q]=v.y*sc; }
      else        { xr[q]=amp*invN2; xi[q]=0.f; }   // angle(0)=0
    }
    dft8<1>(xr,xi);
#pragma unroll
    for(int i=0;i<8;i++){ int e=8*m+i; sld[e*33+c]=__float22half2_rn(make_float2(xr[i],xi[i])); }
  }
  __syncthreads();
#pragma unroll
  for(int jj=0;jj<2;jj++){                      // phase B: inverse stage 1 in LDS
    int m = jj*32 + w;
    int bb = m>>3, nn = m&7, bs = 64*bb+nn;
    float xr[8], xi[8];
#pragma unroll
    for(int q=0;q<8;q++){ int e=bs+8*q; float2 v=__half22float2(sld[e*33+c]); xr[q]=v.x; xi[q]=v.y; }
    twid<1>(xr,xi,nn,1.0f/64.0f);
    dft8<1>(xr,xi);
#pragma unroll
    for(int i=0;i<8;i++){ int e=bs+8*i; sld[e*33+c]=__float22half2_rn(make_float2(xr[i],xi[i])); }
  }
  __syncthreads();
#pragma unroll
  for(int jj=0;jj<2;jj++){                      // phase C: inverse stage 0 -> global (natural h)
    int n = jj*32+w;
    float xr[8], xi[8];
#pragma unroll
    for(int q=0;q<8;q++){ int e=n+64*q; float2 v=__half22float2(sld[e*33+c]); xr[q]=v.x; xi[q]=v.y; }
    twid<1>(xr,xi,n,1.0f/512.0f);
    dft8<1>(xr,xi);
    if(vst){
#pragma unroll
      for(int i=0;i<8;i++){ base[(size_t)(n+64*i)*W2+c]=__float22half2_rn(make_float2(xr[i],xi[i])); }
    }
  }
}

// ---------- K6: paired-row inverse real FFT (128 threads = 2 waves) ----------
// Post-column-inverse rows are Hermitian along w: Y[h,512-w]=conj(Y[h,w]).
__global__ __launch_bounds__(128) void k_row_irfft(const h2* __restrict__ Fh, ull fh_cs,
                                                   float* __restrict__ out){
  __shared__ h2 gA[2][264], gB[2][264];
  __shared__ float lre[2][512], lim[2][512];
  const int wv=threadIdx.x>>6, t=threadIdx.x&63;
  const int pr = blockIdx.x*2+wv;               // b*256 + r2
  const int b = pr>>8, r2 = pr&255;
  const int cc = blockIdx.y;
  const h2* Rp = Fh + (size_t)cc*fh_cs + (size_t)(b*HH + 2*r2)*W2;
  const h2* Rq = Rp + W2;
#pragma unroll
  for(int j=0;j<5;j++){
    int w = t + 64*j;
    if(w<=256){ gA[wv][w]=Rp[w]; gB[wv][w]=Rq[w]; }
  }
  __syncthreads();
  // gather digit-reversed slots: slot 8t+i needs Z[rev9(8t+i)]
  float xr[8], xi[8];
#pragma unroll
  for(int i=0;i<8;i++){
    int w = rev9(8*t+i);
    float zr, zi;
    if(w<=256){
      float2 a = __half22float2(gA[wv][w]);
      float2 bb = __half22float2(gB[wv][w]);
      zr = a.x - bb.y; zi = a.y + bb.x;
    }else{
      int m = 512-w;   // row-wise Hermitian: Z[w] = conj(A[m]) + i*conj(B[m])
      float2 a = __half22float2(gA[wv][m]);
      float2 bb = __half22float2(gB[wv][m]);
      zr = a.x + bb.y; zi = bb.x - a.y;
    }
    xr[i]=zr; xi[i]=zi;
  }
  dft8<1>(xr,xi);                               // inverse of stage 2
#pragma unroll
  for(int i=0;i<8;i++){ int pp=swz(8*t+i); lre[wv][pp]=xr[i]; lim[wv][pp]=xi[i]; }
  __syncthreads();
  const int beta=t>>3, n1=t&7, base1=64*beta+n1;
#pragma unroll
  for(int qq=0;qq<8;qq++){ int pp=swz(base1+8*qq); xr[qq]=lre[wv][pp]; xi[qq]=lim[wv][pp]; }
  twid<1>(xr,xi,n1,1.0f/64.0f);
  dft8<1>(xr,xi);                               // inverse of stage 1
#pragma unroll
  for(int i=0;i<8;i++){ int pp=swz(base1+8*i); lre[wv][pp]=xr[i]; lim[wv][pp]=xi[i]; }
  __syncthreads();
#pragma unroll
  for(int qq=0;qq<8;qq++){ int pp=swz(t+64*qq); xr[qq]=lre[wv][pp]; xi[qq]=lim[wv][pp]; }
  twid<1>(xr,xi,t,1.0f/512.0f);
  dft8<1>(xr,xi);                               // inverse of stage 0 -> natural w
  float* oa = out + (size_t)b*(NC*HH*WW) + (size_t)cc*HH*WW + (size_t)(2*r2)*WW;
  float* ob = oa + WW;
#pragma unroll
  for(int i=0;i<8;i++){ oa[t+64*i]=xr[i]; ob[t+64*i]=xi[i]; }
}

// ---------- launch ----------
extern "C" void kernel_launch(void* const* d_in, const int* in_sizes, int n_in,
                              void* d_out, int out_size, void* d_ws, size_t ws_size,
                              hipStream_t stream) {
  const float* x  = (const float*)d_in[0];        // [32,3,512,512]
  const float* ra = (const float*)d_in[1];        // [3,512,512]
  float* out = (float*)d_out;

  const ull fh_cs = (ull)NB*HH*W2;                 // half2 elems / channel
  const ull a_cs  = (ull)HH*W2;                    // floats / channel
  const size_t fb3 = (size_t)fh_cs*sizeof(h2)*3;   // 53.5 MB
  const size_t ab1 = (size_t)a_cs*sizeof(float);   // 0.56 MB
  // layout: [Fh (3ch, half2)] [rsum (64B)] [A (3ch)]
  const size_t need = fb3 + 64 + 3*ab1;
  if (ws_size < need) return;

  h2*    Fh   = (h2*)d_ws;
  float* rsum = (float*)((char*)d_ws + fb3);
  float* A    = (float*)((char*)rsum + 64);

  hipMemsetAsync(rsum, 0, sizeof(float), stream);
  k_rsum<<<768,256,0,stream>>>(ra, rsum, NC*HH*WW);

  k_row_rfft <<<dim3(NB*256/2,3), 128, 0, stream>>>(x, Fh, fh_cs);
  k_col_fft  <<<dim3(NB*NT,3),   1024, 0, stream>>>(Fh, fh_cs);
  k_amp      <<<dim3(HH*136/256,3),256, 0, stream>>>(Fh, fh_cs, ra, rsum, A, a_cs);
  k_col_ifft <<<dim3(NB*NT,3),   1024, 0, stream>>>(Fh, fh_cs, A, a_cs);
  k_row_irfft<<<dim3(NB*256/2,3), 128, 0, stream>>>(Fh, fh_cs, out);
}

// Round 9
// 193.919 us; speedup vs baseline: 1.0729x; 1.0729x over previous
//
#include <hip/hip_runtime.h>
#include <hip/hip_fp16.h>
#include <math.h>

#define NB 32
#define NC 3
#define HH 512
#define WW 512
#define W2 272   // padded half-spectrum width: cols 0..256 valid, 257..271 pad

typedef __half2 h2;
typedef unsigned long long ull;

// ---------- helpers ----------

// XOR swizzle for per-line LDS FFT: 2-way (free) bank conflicts on all 3 stages
__device__ __forceinline__ int swz(int i){ int h=(i>>6)&7; return i ^ (h<<3) ^ h; }
// base-8 digit reversal of 9-bit index
__device__ __forceinline__ int rev9(int k){ return ((k&7)<<6) | (k&56) | (k>>6); }

__device__ __forceinline__ float sin2pi(float x){
#if __has_builtin(__builtin_amdgcn_sinf)
  return __builtin_amdgcn_sinf(x);
#else
  return __sinf(6.28318530717958647692f*x);
#endif
}
__device__ __forceinline__ float cos2pi(float x){
#if __has_builtin(__builtin_amdgcn_cosf)
  return __builtin_amdgcn_cosf(x);
#else
  return __cosf(6.28318530717958647692f*x);
#endif
}

// unnormalized 8-point DFT. S=-1: forward; S=+1: conjugate (8*inverse)
template<int S>
__device__ __forceinline__ void dft8(float* xr, float* xi){
  const float r2 = 0.70710678118654752f;
  float tr[4], ti[4], mr[4], mi[4];
#pragma unroll
  for(int n=0;n<4;n++){
    tr[n]=xr[n]+xr[n+4]; ti[n]=xi[n]+xi[n+4];
    mr[n]=xr[n]-xr[n+4]; mi[n]=xi[n]-xi[n+4];
  }
  float or_[4], oi_[4];
  or_[0]=mr[0];               oi_[0]=mi[0];
  or_[1]=r2*(mr[1]-S*mi[1]);  oi_[1]=r2*(mi[1]+S*mr[1]);
  or_[2]=-S*mi[2];            oi_[2]= S*mr[2];
  or_[3]=-r2*(mr[3]+S*mi[3]); oi_[3]= r2*(S*mr[3]-mi[3]);
  float s0r=tr[0]+tr[2], s0i=ti[0]+ti[2];
  float s1r=tr[1]+tr[3], s1i=ti[1]+ti[3];
  float d0r=tr[0]-tr[2], d0i=ti[0]-ti[2];
  float d1r=tr[1]-tr[3], d1i=ti[1]-ti[3];
  xr[0]=s0r+s1r;   xi[0]=s0i+s1i;
  xr[4]=s0r-s1r;   xi[4]=s0i-s1i;
  xr[2]=d0r-S*d1i; xi[2]=d0i+S*d1r;
  xr[6]=d0r+S*d1i; xi[6]=d0i-S*d1r;
  float p0r=or_[0]+or_[2], p0i=oi_[0]+oi_[2];
  float p1r=or_[1]+or_[3], p1i=oi_[1]+oi_[3];
  float e0r=or_[0]-or_[2], e0i=oi_[0]-oi_[2];
  float e1r=or_[1]-or_[3], e1i=oi_[1]-oi_[3];
  xr[1]=p0r+p1r;   xi[1]=p0i+p1i;
  xr[5]=p0r-p1r;   xi[5]=p0i-p1i;
  xr[3]=e0r-S*e1i; xi[3]=e0i+S*e1r;
  xr[7]=e0r+S*e1i; xi[7]=e0i-S*e1r;
}

template<int S>
__device__ __forceinline__ void twid(float* xr, float* xi, int n, float invM){
  float f = (float)n * invM;
  float c1 = cos2pi(f), s1 = (float)S * sin2pi(f);
  float cr=c1, ci=s1;
#pragma unroll
  for(int q=1;q<8;q++){
    float a=xr[q], b=xi[q];
    xr[q]=a*cr-b*ci; xi[q]=a*ci+b*cr;
    float nr=cr*c1-ci*s1, ni=cr*s1+ci*c1;
    cr=nr; ci=ni;
  }
}

// ---------- K1: paired-row real FFT -> half spectrum (half2, natural w 0..256) ----------
// 128 threads = 2 independent waves, per-wave LDS regions
__global__ __launch_bounds__(128) void k_row_rfft(const float* __restrict__ x, h2* __restrict__ Fh,
                                                  ull fh_cs){
  __shared__ float lre[2][512];
  __shared__ float lim[2][512];
  const int wv = threadIdx.x>>6, t = threadIdx.x&63;
  const int pr = blockIdx.x*2 + wv;             // pair index: b*256 + r2
  const int b = pr>>8, r2 = pr&255;
  const int cc = blockIdx.y;
  const float* sa = x + (size_t)b*(NC*HH*WW) + (size_t)cc*HH*WW + (size_t)(2*r2)*WW;
  const float* sb = sa + WW;
  float xr[8], xi[8];
#pragma unroll
  for(int i=0;i<8;i++){ xr[i]=sa[t+64*i]; xi[i]=sb[t+64*i]; }
  dft8<-1>(xr,xi);
  twid<-1>(xr,xi,t,1.0f/512.0f);
#pragma unroll
  for(int q=0;q<8;q++){ int p=swz(t+64*q); lre[wv][p]=xr[q]; lim[wv][p]=xi[q]; }
  __syncthreads();
  const int beta=t>>3, n1=t&7, base1=64*beta+n1;
#pragma unroll
  for(int i=0;i<8;i++){ int p=swz(base1+8*i); xr[i]=lre[wv][p]; xi[i]=lim[wv][p]; }
  dft8<-1>(xr,xi);
  twid<-1>(xr,xi,n1,1.0f/64.0f);
#pragma unroll
  for(int q=0;q<8;q++){ int p=swz(base1+8*q); lre[wv][p]=xr[q]; lim[wv][p]=xi[q]; }
  __syncthreads();
#pragma unroll
  for(int i=0;i<8;i++){ int p=swz(8*t+i); xr[i]=lre[wv][p]; xi[i]=lim[wv][p]; }
  dft8<-1>(xr,xi);
  __syncthreads();
  // scatter to natural order: slot 8t+i holds Z[rev9(8t+i)]
#pragma unroll
  for(int i=0;i<8;i++){ int nat = 64*i + 8*(t&7) + (t>>3); lre[wv][nat]=xr[i]; lim[wv][nat]=xi[i]; }
  __syncthreads();
  // Hermitian unpack: Ra[w]=(Z[w]+conj(Z[-w]))/2, Rb[w]=-i(Z[w]-conj(Z[-w]))/2
  h2* Fa = Fh + (size_t)cc*fh_cs + (size_t)(b*HH + 2*r2)*W2;
  h2* Fb = Fa + W2;
#pragma unroll
  for(int j=0;j<5;j++){
    int w = t + 64*j;
    if(w<=256){
      int m = (512-w)&511;
      float pr_=lre[wv][w], pi_=lim[wv][w], qr=lre[wv][m], qi=lim[wv][m];
      Fa[w]=__float22half2_rn(make_float2(0.5f*(pr_+qr), 0.5f*(pi_-qi)));
      Fb[w]=__float22half2_rn(make_float2(0.5f*(pi_+qi), 0.5f*(qr-pr_)));
    }
  }
}

// ---------- K2: column FFT (3-phase, h2-packed LDS, 4 blocks/CU) ----------
__global__ __launch_bounds__(512, 8) void k_col_fft(h2* __restrict__ Fh, ull fh_cs){
  __shared__ h2 sld[512*17];                    // 34.8 KB -> 4 blocks/CU, 32 waves/CU
  const int b    = blockIdx.x/17;
  const int tile = blockIdx.x - b*17;
  const int w0   = tile*16;
  const int cc   = blockIdx.y;
  h2* base = Fh + (size_t)cc*fh_cs + (size_t)b*HH*W2 + w0;
  const int c = threadIdx.x&15, w = threadIdx.x>>4;   // w in 0..31
#pragma unroll
  for(int jj=0;jj<2;jj++){                      // phase A: stage 0 from global
    int n = jj*32 + w;
    float xr[8], xi[8];
#pragma unroll
    for(int i=0;i<8;i++){ float2 v = __half22float2(base[(size_t)(n+64*i)*W2 + c]); xr[i]=v.x; xi[i]=v.y; }
    dft8<-1>(xr,xi);
    twid<-1>(xr,xi,n,1.0f/512.0f);
#pragma unroll
    for(int q=0;q<8;q++){ int e=n+64*q; sld[e*17+c]=__float22half2_rn(make_float2(xr[q],xi[q])); }
  }
  __syncthreads();
#pragma unroll
  for(int jj=0;jj<2;jj++){                      // phase B: stage 1 in LDS
    int m = jj*32 + w;
    int bb = m>>3, nn = m&7, bs = 64*bb+nn;
    float xr[8], xi[8];
#pragma unroll
    for(int i=0;i<8;i++){ int e=bs+8*i; float2 v=__half22float2(sld[e*17+c]); xr[i]=v.x; xi[i]=v.y; }
    dft8<-1>(xr,xi);
    twid<-1>(xr,xi,nn,1.0f/64.0f);
#pragma unroll
    for(int q=0;q<8;q++){ int e=bs+8*q; sld[e*17+c]=__float22half2_rn(make_float2(xr[q],xi[q])); }
  }
  __syncthreads();
#pragma unroll
  for(int jj=0;jj<2;jj++){                      // phase C: stage 2 -> global
    int m = jj*32+w;
    float xr[8], xi[8];
#pragma unroll
    for(int i=0;i<8;i++){ int e=8*m+i; float2 v=__half22float2(sld[e*17+c]); xr[i]=v.x; xi[i]=v.y; }
    dft8<-1>(xr,xi);
    if(w0+c<=256){
#pragma unroll
      for(int q=0;q<8;q++){
        int p=8*m+q;
        base[(size_t)p*W2+c]=__float22half2_rn(make_float2(xr[q],xi[q]));
      }
    }
  }
}

// ---------- K3: sum(running_amp) ----------
__global__ __launch_bounds__(256) void k_rsum(const float* __restrict__ ra, float* __restrict__ out, int n){
  float s=0.f;
  for(int i=blockIdx.x*256+threadIdx.x; i<n; i+=gridDim.x*256) s+=ra[i];
#pragma unroll
  for(int off=32;off>=1;off>>=1) s += __shfl_down(s, off, 64);
  if((threadIdx.x&63)==0) atomicAdd(out, s);
}

// ---------- K4: batch-mean |F| + symmetrized EMA amplitude A (float2-vectorized) ----------
__global__ __launch_bounds__(256) void k_amp(const h2* __restrict__ Fh, ull fh_cs,
                                             const float* __restrict__ ra, const float* __restrict__ rsum,
                                             float* __restrict__ A, ull a_cs){
  int f2 = blockIdx.x*256 + threadIdx.x;        // 0 .. 512*136-1 (pairs of cols)
  int p = f2/136, w2 = f2 - p*136;              // p = digit-rev h slot
  int w = 2*w2;                                 // natural col (even)
  const int cc = blockIdx.y;
  const float2* Fc = (const float2*)(Fh + (size_t)cc*fh_cs);
  float s0=0.f, s1=0.f;
#pragma unroll 8
  for(int b=0;b<NB;b++){
    float2 two = Fc[(size_t)b*(HH*W2/2) + f2];
    h2 va = ((const h2*)&two)[0], vb = ((const h2*)&two)[1];
    float2 a = __half22float2(va), bq = __half22float2(vb);
    s0 += sqrtf(a.x*a.x + a.y*a.y);
    s1 += sqrtf(bq.x*bq.x + bq.y*bq.y);
  }
  float mean0 = s0*(1.0f/32.0f), mean1 = s1*(1.0f/32.0f);
  const float* rac = ra + (size_t)cc*HH*WW;
  int h = rev9(p);
  int hs =(h+256)&511, hs2=(256-h)&511;
  int ws0 =(w+256)&511, ws20=(256-w)&511;
  int ws1 =(w+257)&511, ws21=(255-w)&511;
  float a0, a1;
  if(rsum[0]==0.0f){ a0=mean0; a1=mean1; }
  else{
    a0 = 0.45f*(rac[hs*WW+ws0] + rac[hs2*WW+ws20]) + 0.1f*mean0;
    a1 = 0.45f*(rac[hs*WW+ws1] + rac[hs2*WW+ws21]) + 0.1f*mean1;
  }
  *(float2*)(A + (size_t)cc*a_cs + (size_t)p*W2 + w) = make_float2(a0, a1);
}

// ---------- K5: magnitude substitution + column IFFT (3-phase, h2 LDS) ----------
__global__ __launch_bounds__(512, 8) void k_col_ifft(h2* __restrict__ Fh, ull fh_cs,
                                                     const float* __restrict__ A, ull a_cs){
  __shared__ h2 sld[512*17];
  const int b    = blockIdx.x/17;
  const int tile = blockIdx.x - b*17;
  const int w0   = tile*16;
  const int cc   = blockIdx.y;
  h2* base = Fh + (size_t)cc*fh_cs + (size_t)b*HH*W2 + w0;
  const float* Aa = A + (size_t)cc*a_cs + w0;
  const int c = threadIdx.x&15, w = threadIdx.x>>4;
  const float invN2 = 1.0f/262144.0f;
#pragma unroll
  for(int jj=0;jj<2;jj++){                      // phase A: scale + inverse stage 2, from global
    int m = jj*32+w;
    float xr[8], xi[8];
#pragma unroll
    for(int q=0;q<8;q++){
      int p=8*m+q;
      float2 v = __half22float2(base[(size_t)p*W2+c]);
      float amp = Aa[(size_t)p*W2+c];
      float m2 = v.x*v.x + v.y*v.y;
      float sc = amp*invN2*__frsqrt_rn(m2);
      if(m2 > 0.f){ xr[q]=v.x*sc; xi[q]=v.y*sc; }
      else        { xr[q]=amp*invN2; xi[q]=0.f; }   // angle(0)=0
    }
    dft8<1>(xr,xi);
#pragma unroll
    for(int i=0;i<8;i++){ int e=8*m+i; sld[e*17+c]=__float22half2_rn(make_float2(xr[i],xi[i])); }
  }
  __syncthreads();
#pragma unroll
  for(int jj=0;jj<2;jj++){                      // phase B: inverse stage 1 in LDS
    int m = jj*32 + w;
    int bb = m>>3, nn = m&7, bs = 64*bb+nn;
    float xr[8], xi[8];
#pragma unroll
    for(int q=0;q<8;q++){ int e=bs+8*q; float2 v=__half22float2(sld[e*17+c]); xr[q]=v.x; xi[q]=v.y; }
    twid<1>(xr,xi,nn,1.0f/64.0f);
    dft8<1>(xr,xi);
#pragma unroll
    for(int i=0;i<8;i++){ int e=bs+8*i; sld[e*17+c]=__float22half2_rn(make_float2(xr[i],xi[i])); }
  }
  __syncthreads();
#pragma unroll
  for(int jj=0;jj<2;jj++){                      // phase C: inverse stage 0 -> global (natural h)
    int n = jj*32+w;
    float xr[8], xi[8];
#pragma unroll
    for(int q=0;q<8;q++){ int e=n+64*q; float2 v=__half22float2(sld[e*17+c]); xr[q]=v.x; xi[q]=v.y; }
    twid<1>(xr,xi,n,1.0f/512.0f);
    dft8<1>(xr,xi);
    if(w0+c<=256){
#pragma unroll
      for(int i=0;i<8;i++){ base[(size_t)(n+64*i)*W2+c]=__float22half2_rn(make_float2(xr[i],xi[i])); }
    }
  }
}

// ---------- K6: paired-row inverse real FFT (128 threads = 2 waves) ----------
// Post-column-inverse rows are Hermitian along w: Y[h,512-w]=conj(Y[h,w]).
__global__ __launch_bounds__(128) void k_row_irfft(const h2* __restrict__ Fh, ull fh_cs,
                                                   float* __restrict__ out){
  __shared__ h2 gA[2][264], gB[2][264];
  __shared__ float lre[2][512], lim[2][512];
  const int wv=threadIdx.x>>6, t=threadIdx.x&63;
  const int pr = blockIdx.x*2+wv;               // b*256 + r2
  const int b = pr>>8, r2 = pr&255;
  const int cc = blockIdx.y;
  const h2* Rp = Fh + (size_t)cc*fh_cs + (size_t)(b*HH + 2*r2)*W2;
  const h2* Rq = Rp + W2;
#pragma unroll
  for(int j=0;j<5;j++){
    int w = t + 64*j;
    if(w<=256){ gA[wv][w]=Rp[w]; gB[wv][w]=Rq[w]; }
  }
  __syncthreads();
  // gather digit-reversed slots: slot 8t+i needs Z[rev9(8t+i)]
  float xr[8], xi[8];
#pragma unroll
  for(int i=0;i<8;i++){
    int w = rev9(8*t+i);
    float zr, zi;
    if(w<=256){
      float2 a = __half22float2(gA[wv][w]);
      float2 bb = __half22float2(gB[wv][w]);
      zr = a.x - bb.y; zi = a.y + bb.x;
    }else{
      int m = 512-w;   // row-wise Hermitian: Z[w] = conj(A[m]) + i*conj(B[m])
      float2 a = __half22float2(gA[wv][m]);
      float2 bb = __half22float2(gB[wv][m]);
      zr = a.x + bb.y; zi = bb.x - a.y;
    }
    xr[i]=zr; xi[i]=zi;
  }
  dft8<1>(xr,xi);                               // inverse of stage 2
#pragma unroll
  for(int i=0;i<8;i++){ int pp=swz(8*t+i); lre[wv][pp]=xr[i]; lim[wv][pp]=xi[i]; }
  __syncthreads();
  const int beta=t>>3, n1=t&7, base1=64*beta+n1;
#pragma unroll
  for(int qq=0;qq<8;qq++){ int pp=swz(base1+8*qq); xr[qq]=lre[wv][pp]; xi[qq]=lim[wv][pp]; }
  twid<1>(xr,xi,n1,1.0f/64.0f);
  dft8<1>(xr,xi);                               // inverse of stage 1
#pragma unroll
  for(int i=0;i<8;i++){ int pp=swz(base1+8*i); lre[wv][pp]=xr[i]; lim[wv][pp]=xi[i]; }
  __syncthreads();
#pragma unroll
  for(int qq=0;qq<8;qq++){ int pp=swz(t+64*qq); xr[qq]=lre[wv][pp]; xi[qq]=lim[wv][pp]; }
  twid<1>(xr,xi,t,1.0f/512.0f);
  dft8<1>(xr,xi);                               // inverse of stage 0 -> natural w
  float* oa = out + (size_t)b*(NC*HH*WW) + (size_t)cc*HH*WW + (size_t)(2*r2)*WW;
  float* ob = oa + WW;
#pragma unroll
  for(int i=0;i<8;i++){ oa[t+64*i]=xr[i]; ob[t+64*i]=xi[i]; }
}

// ---------- launch ----------
extern "C" void kernel_launch(void* const* d_in, const int* in_sizes, int n_in,
                              void* d_out, int out_size, void* d_ws, size_t ws_size,
                              hipStream_t stream) {
  const float* x  = (const float*)d_in[0];        // [32,3,512,512]
  const float* ra = (const float*)d_in[1];        // [3,512,512]
  float* out = (float*)d_out;

  const ull fh_cs = (ull)NB*HH*W2;                 // half2 elems / channel
  const ull a_cs  = (ull)HH*W2;                    // floats / channel
  const size_t fb3 = (size_t)fh_cs*sizeof(h2)*3;   // 53.5 MB
  const size_t ab1 = (size_t)a_cs*sizeof(float);   // 0.56 MB
  // layout: [Fh (3ch, half2)] [rsum (64B)] [A (3ch)]
  const size_t need = fb3 + 64 + 3*ab1;
  if (ws_size < need) return;

  h2*    Fh   = (h2*)d_ws;
  float* rsum = (float*)((char*)d_ws + fb3);
  float* A    = (float*)((char*)rsum + 64);

  hipMemsetAsync(rsum, 0, sizeof(float), stream);
  k_rsum<<<768,256,0,stream>>>(ra, rsum, NC*HH*WW);

  k_row_rfft <<<dim3(NB*256/2,3), 128, 0, stream>>>(x, Fh, fh_cs);
  k_col_fft  <<<dim3(NB*17,3),    512, 0, stream>>>(Fh, fh_cs);
  k_amp      <<<dim3(HH*136/256,3),256, 0, stream>>>(Fh, fh_cs, ra, rsum, A, a_cs);
  k_col_ifft <<<dim3(NB*17,3),    512, 0, stream>>>(Fh, fh_cs, A, a_cs);
  k_row_irfft<<<dim3(NB*256/2,3), 128, 0, stream>>>(Fh, fh_cs, out);
}